// Round 5
// baseline (765.037 us; speedup 1.0000x reference)
//
#include <hip/hip_runtime.h>

typedef __bf16 bf16_t;
typedef __bf16 bf16x8 __attribute__((ext_vector_type(8)));
typedef float  f32x4  __attribute__((ext_vector_type(4)));

#define S_LEN 2048
#define NH    16
#define DH    64
#define DM    1024
#define BATCH 4

static __device__ __forceinline__ f32x4 mfma16(bf16x8 a, bf16x8 b, f32x4 c) {
    return __builtin_amdgcn_mfma_f32_16x16x32_bf16(a, b, c, 0, 0, 0);
}

// async global->LDS, 16B per lane. lds base is wave-uniform; HW adds lane*16.
static __device__ __forceinline__ void gl_lds16(const bf16_t* g, bf16_t* l) {
    __builtin_amdgcn_global_load_lds(
        (const __attribute__((address_space(1))) unsigned int*)g,
        (__attribute__((address_space(3))) unsigned int*)l, 16, 0, 0);
}

// ---------------- fp32 -> bf16 elementwise convert (8 elems/thread) ----------
__global__ __launch_bounds__(256) void cvt_bf16(const float* __restrict__ s,
                                                bf16_t* __restrict__ d, int n) {
    int i = (blockIdx.x * 256 + threadIdx.x) * 8;
    if (i >= n) return;
    const float4* q = (const float4*)(s + i);
    float4 a = q[0], b = q[1];
    bf16x8 r;
    r[0] = (bf16_t)a.x; r[1] = (bf16_t)a.y; r[2] = (bf16_t)a.z; r[3] = (bf16_t)a.w;
    r[4] = (bf16_t)b.x; r[5] = (bf16_t)b.y; r[6] = (bf16_t)b.z; r[7] = (bf16_t)b.w;
    *(bf16x8*)(d + i) = r;
}

// ---------------- weight transpose+convert: Wt[n][k] = scale * W[k][n] -------
__global__ __launch_bounds__(256) void wtrans(const float* __restrict__ W,
                                              bf16_t* __restrict__ Wt, float scale) {
    __shared__ bf16_t tile[32][33];
    int x = threadIdx.x, ty = threadIdx.y;
    int bx = blockIdx.x * 32, by = blockIdx.y * 32;
#pragma unroll
    for (int i = 0; i < 4; ++i) {
        int y = ty * 4 + i;
        tile[y][x] = (bf16_t)(W[(by + y) * DM + bx + x] * scale);
    }
    __syncthreads();
#pragma unroll
    for (int i = 0; i < 4; ++i) {
        int y = ty * 4 + i;
        Wt[(bx + y) * DM + by + x] = tile[x][y];
    }
}

// ---------------- bf16 transpose: dst[C][R] = src[R][C] ----------------------
__global__ __launch_bounds__(256) void btrans(const bf16_t* __restrict__ src,
                                              bf16_t* __restrict__ dst,
                                              int R, int C) {
    __shared__ bf16_t tile[32][33];
    int x = threadIdx.x, ty = threadIdx.y;
    int bx = blockIdx.x * 32, by = blockIdx.y * 32;   // bx: col, by: row
#pragma unroll
    for (int i = 0; i < 4; ++i) {
        int y = ty * 4 + i;
        tile[y][x] = src[(size_t)(by + y) * C + bx + x];
    }
    __syncthreads();
#pragma unroll
    for (int i = 0; i < 4; ++i) {
        int y = ty * 4 + i;
        dst[(size_t)(bx + y) * R + by + x] = tile[x][y];
    }
}

// ---------------- NT GEMM (m97 structure): C = alpha * A[M][K] . Bt[N][K]^T --
// 128x128 tile, BK=32, global_load_lds width-16 staging, 4 waves, 4x4 frags.
template <typename CT>
__global__ __launch_bounds__(256) void gemm_nt_128(const bf16_t* __restrict__ A,
                                                   const bf16_t* __restrict__ Bt,
                                                   CT* __restrict__ C,
                                                   int M, int N, int K, float alpha) {
    __shared__ __align__(16) bf16_t As[128 * 32];  // unpadded: global_load_lds layout
    __shared__ __align__(16) bf16_t Bs[128 * 32];
    int tid = threadIdx.x, wave = tid >> 6, lane = tid & 63;
    int l15 = lane & 15, quad = lane >> 4;
    int wm = wave >> 1, wn = wave & 1;
    int bm = blockIdx.x * 128, bn = blockIdx.y * 128;
    int lrow = lane >> 2, lk = (lane & 3) << 3;

    f32x4 acc[4][4] = {};

    for (int k0 = 0; k0 < K; k0 += 32) {
#pragma unroll
        for (int c = 0; c < 2; ++c) {
            int r = wave * 32 + c * 16 + lrow;            // tile row this lane fetches
            gl_lds16(A  + (size_t)(bm + r) * K + k0 + lk, As + (wave * 2 + c) * 512);
            gl_lds16(Bt + (size_t)(bn + r) * K + k0 + lk, Bs + (wave * 2 + c) * 512);
        }
        __syncthreads();   // compiler drains vmcnt before s_barrier

        bf16x8 af[4], bfr[4];
#pragma unroll
        for (int i = 0; i < 4; ++i)
            af[i] = *(const bf16x8*)(As + (wm * 64 + i * 16 + l15) * 32 + quad * 8);
#pragma unroll
        for (int j = 0; j < 4; ++j)
            bfr[j] = *(const bf16x8*)(Bs + (wn * 64 + j * 16 + l15) * 32 + quad * 8);
#pragma unroll
        for (int i = 0; i < 4; ++i)
#pragma unroll
            for (int j = 0; j < 4; ++j)
                acc[i][j] = mfma16(af[i], bfr[j], acc[i][j]);
        __syncthreads();
    }

#pragma unroll
    for (int i = 0; i < 4; ++i)
#pragma unroll
        for (int r = 0; r < 4; ++r) {
            int row = bm + wm * 64 + i * 16 + quad * 4 + r;
#pragma unroll
            for (int j = 0; j < 4; ++j)
                C[(size_t)row * N + bn + wn * 64 + j * 16 + l15] =
                    (CT)(acc[i][j][r] * alpha);
        }
}

// ---------------- per-batch V column mean (for fully-masked-row fallback) ----
__global__ __launch_bounds__(256) void vmean_kernel(const bf16_t* __restrict__ Vp,
                                                    float* __restrict__ Vm) {
    __shared__ float red[4][64];
    int z = blockIdx.y;
    int c = blockIdx.x * 64 + (threadIdx.x & 63);
    int rg = threadIdx.x >> 6;
    const bf16_t* p = Vp + (size_t)z * S_LEN * DM + (size_t)rg * (S_LEN / 4) * DM + c;
    float s = 0.f;
    for (int r = 0; r < S_LEN / 4; ++r) s += (float)p[(size_t)r * DM];
    red[rg][threadIdx.x & 63] = s;
    __syncthreads();
    if (threadIdx.x < 64) {
        float t = red[0][threadIdx.x] + red[1][threadIdx.x] +
                  red[2][threadIdx.x] + red[3][threadIdx.x];
        Vm[z * DM + blockIdx.x * 64 + threadIdx.x] = t * (1.0f / S_LEN);
    }
}

// ---------------- fused attention, global-frag version ----------------------
// grid (S/64, NH, nb). K frags direct from Kp [s][h*64+dh]; V frags direct from
// VT [h*64+dh][ldv] (pre-transposed). No barriers in the K-loop; only LDS use
// is the per-wave-private P layout round-trip (stride 72 = 16B-aligned rows,
// phase-conflict-free b128 reads). Mask semantics exact as before; rows with
// no unmasked key fall back to Vmean (uniform softmax over all 2048 keys).
// ctx may alias Qp: block reads only its own (rows x head) slice at start and
// writes only that same slice at the end; slices are disjoint across blocks.
__global__ __launch_bounds__(256) void attn_kernel(const bf16_t* __restrict__ Qp,
                                                   const bf16_t* __restrict__ Kp,
                                                   const bf16_t* __restrict__ VT,
                                                   const int* __restrict__ Kini,
                                                   const float* __restrict__ Vmean,
                                                   bf16_t* __restrict__ ctx,
                                                   int ldv) {
    __shared__ __align__(16) bf16_t Ps[4][16 * 72];  // per-wave P [qrow][key]

    int qt = gridDim.x - 1 - blockIdx.x;             // heavy tiles first
    int h = blockIdx.y, z = blockIdx.z;
    int tid = threadIdx.x, wave = tid >> 6, lane = tid & 63;
    int l15 = lane & 15, quad = lane >> 4;
    int qbase = qt * 64 + wave * 16;
    size_t rowz = (size_t)z * S_LEN;

    const bf16_t* qptr = Qp + (rowz + qbase + l15) * DM + h * DH + quad * 8;
    bf16x8 qa0 = *(const bf16x8*)qptr;
    bf16x8 qa1 = *(const bf16x8*)(qptr + 32);

    // per-iteration base pointers (advance by 64 rows / 64 cols per tile)
    const bf16_t* kg0 = Kp + (rowz + l15) * DM + h * DH + quad * 8;
    const bf16_t* vg0 = VT + (size_t)(h * DH + l15) * ldv + rowz + quad * 8;
    const int* ki0 = Kini + rowz + l15;

    f32x4 o[4] = {};
    float m_[4], l_[4];
#pragma unroll
    for (int r = 0; r < 4; ++r) { m_[r] = -3.0e38f; l_[r] = 0.0f; }

    int ntiles = qt + 1;                             // causal: only kb <= q_max
    for (int kt = 0; kt < ntiles; ++kt) {
        int kb = kt * 64;
        const bf16_t* kg = kg0 + (size_t)kb * DM;

        // K fragments: B-frag lane (n=l15 -> key, k=quad*8+j -> dh)
        bf16x8 kf0[4], kf1[4];
#pragma unroll
        for (int ks = 0; ks < 4; ++ks) {
            kf0[ks] = *(const bf16x8*)(kg + (size_t)(ks * 16) * DM);
            kf1[ks] = *(const bf16x8*)(kg + (size_t)(ks * 16) * DM + 32);
        }
        // V fragments issued early: B-frag lane (n=l15 -> dh, k=quad*8+j -> key)
        bf16x8 vf0[4], vf1[4];
#pragma unroll
        for (int j = 0; j < 4; ++j) {
            const bf16_t* vg = vg0 + (size_t)(j * 16) * ldv + kb;
            vf0[j] = *(const bf16x8*)vg;
            vf1[j] = *(const bf16x8*)(vg + 32);
        }

        float sv[4][4];
#pragma unroll
        for (int ks = 0; ks < 4; ++ks) {
            f32x4 s = {0.f, 0.f, 0.f, 0.f};
            s = mfma16(qa0, kf0[ks], s);
            s = mfma16(qa1, kf1[ks], s);
            int key = kb + ks * 16 + l15;
            bool padz = (ki0[kb + ks * 16] == 0);
#pragma unroll
            for (int r = 0; r < 4; ++r) {
                int q = qbase + quad * 4 + r;
                float val = s[r];
                if (padz || key > q) val -= 1e10f;   // additive mask, exact ref
                sv[ks][r] = val;
            }
        }

        // online softmax (stats reduced over the 16 lanes of each quad group)
#pragma unroll
        for (int r = 0; r < 4; ++r) {
            float mx = fmaxf(fmaxf(sv[0][r], sv[1][r]), fmaxf(sv[2][r], sv[3][r]));
#pragma unroll
            for (int d = 1; d < 16; d <<= 1) mx = fmaxf(mx, __shfl_xor(mx, d));
            float mn = fmaxf(m_[r], mx);
            float al = __expf(m_[r] - mn);
            float p0 = __expf(sv[0][r] - mn), p1 = __expf(sv[1][r] - mn);
            float p2 = __expf(sv[2][r] - mn), p3 = __expf(sv[3][r] - mn);
            float rs = (p0 + p1) + (p2 + p3);
#pragma unroll
            for (int d = 1; d < 16; d <<= 1) rs += __shfl_xor(rs, d);
            l_[r] = l_[r] * al + rs;
            m_[r] = mn;
#pragma unroll
            for (int j = 0; j < 4; ++j) o[j][r] *= al;
            int pr = (quad * 4 + r) * 72;
            Ps[wave][pr + l15]      = (bf16_t)p0;
            Ps[wave][pr + 16 + l15] = (bf16_t)p1;
            Ps[wave][pr + 32 + l15] = (bf16_t)p2;
            Ps[wave][pr + 48 + l15] = (bf16_t)p3;
        }

        // P (C-layout) -> A-layout via per-wave LDS round-trip (no barrier:
        // same-wave ds ordering, compiler inserts lgkmcnt)
        bf16x8 pa0 = *(const bf16x8*)(Ps[wave] + l15 * 72 + quad * 8);
        bf16x8 pa1 = *(const bf16x8*)(Ps[wave] + l15 * 72 + 32 + quad * 8);
#pragma unroll
        for (int j = 0; j < 4; ++j) {
            o[j] = mfma16(pa0, vf0[j], o[j]);
            o[j] = mfma16(pa1, vf1[j], o[j]);
        }
    }

#pragma unroll
    for (int r = 0; r < 4; ++r) {
        int q = qbase + quad * 4 + r;
        float inv = 1.0f / l_[r];
        bf16_t* cp = ctx + (rowz + q) * DM + h * DH;
        if (m_[r] < -1e9f) {  // fully-masked row: ref softmax uniform over 2048
            const float* vm = Vmean + z * DM + h * DH;
#pragma unroll
            for (int j = 0; j < 4; ++j) cp[j * 16 + l15] = (bf16_t)vm[j * 16 + l15];
        } else {
#pragma unroll
            for (int j = 0; j < 4; ++j) cp[j * 16 + l15] = (bf16_t)(o[j][r] * inv);
        }
    }
}

extern "C" void kernel_launch(void* const* d_in, const int* in_sizes, int n_in,
                              void* d_out, int out_size, void* d_ws, size_t ws_size,
                              hipStream_t stream) {
    const float* Qe = (const float*)d_in[0];
    const float* Ke = (const float*)d_in[1];
    const float* Ve = (const float*)d_in[2];
    const int* Kini = (const int*)d_in[4];
    const float* WQ = (const float*)d_in[5];
    const float* WK = (const float*)d_in[6];
    const float* WV = (const float*)d_in[7];
    const float* WO = (const float*)d_in[8];
    float* out = (float*)d_out;

    const size_t EMB = (size_t)BATCH * S_LEN * DM;   // 8M elems
    const size_t SB  = (size_t)S_LEN * DM;           // 2M elems
    const size_t WSZ = (size_t)DM * DM;              // 1M elems
    const size_t need_full = (6 * EMB + 4 * WSZ) * sizeof(bf16_t)
                           + (size_t)BATCH * DM * sizeof(float);

    dim3 tb32(32, 8), tg32(32, 32);

    if (ws_size >= need_full) {
        // ---- full-batch path (M = 8192) ----
        bf16_t* Qb  = (bf16_t*)d_ws;
        bf16_t* Kb  = Qb + EMB;
        bf16_t* Vb  = Kb + EMB;                 // becomes VT after V-GEMM
        bf16_t* WQt = Vb + EMB;
        bf16_t* WKt = WQt + WSZ;
        bf16_t* WVt = WKt + WSZ;
        bf16_t* WOt = WVt + WSZ;
        bf16_t* Qp  = WOt + WSZ;
        bf16_t* Kp  = Qp + EMB;
        bf16_t* Vp  = Kp + EMB;
        float*  Vm  = (float*)(Vp + EMB);
        bf16_t* Cx  = Qp;   // alias, block-disjoint (see attn_kernel)
        bf16_t* VT  = Vb;   // reuse spent Vb buffer

        int cg = (int)(EMB / (8 * 256));
        cvt_bf16<<<cg, 256, 0, stream>>>(Qe, Qb, (int)EMB);
        cvt_bf16<<<cg, 256, 0, stream>>>(Ke, Kb, (int)EMB);
        cvt_bf16<<<cg, 256, 0, stream>>>(Ve, Vb, (int)EMB);
        wtrans<<<tg32, tb32, 0, stream>>>(WQ, WQt, 0.125f);  // fold 1/sqrt(dh)
        wtrans<<<tg32, tb32, 0, stream>>>(WK, WKt, 1.0f);
        wtrans<<<tg32, tb32, 0, stream>>>(WV, WVt, 1.0f);
        wtrans<<<tg32, tb32, 0, stream>>>(WO, WOt, 1.0f);

        dim3 gg(8192 / 128, DM / 128);
        gemm_nt_128<bf16_t><<<gg, 256, 0, stream>>>(Qb, WQt, Qp, 8192, DM, DM, 1.0f);
        gemm_nt_128<bf16_t><<<gg, 256, 0, stream>>>(Kb, WKt, Kp, 8192, DM, DM, 1.0f);
        gemm_nt_128<bf16_t><<<gg, 256, 0, stream>>>(Vb, WVt, Vp, 8192, DM, DM, 1.0f);

        btrans<<<dim3(DM / 32, 8192 / 32), tb32, 0, stream>>>(Vp, VT, 8192, DM);
        vmean_kernel<<<dim3(DM / 64, BATCH), 256, 0, stream>>>(Vp, Vm);
        attn_kernel<<<dim3(S_LEN / 64, NH, BATCH), 256, 0, stream>>>(
            Qp, Kp, VT, Kini, Vm, Cx, 8192);

        gemm_nt_128<float><<<gg, 256, 0, stream>>>(Cx, WOt, out, 8192, DM, DM, 1.0f);
    } else {
        // ---- per-batch fallback (M = 2048, ~34 MB workspace) ----
        bf16_t* Qb  = (bf16_t*)d_ws;
        bf16_t* Kb  = Qb + SB;
        bf16_t* Vb  = Kb + SB;
        bf16_t* WQt = Vb + SB;
        bf16_t* WKt = WQt + WSZ;
        bf16_t* WVt = WKt + WSZ;
        bf16_t* WOt = WVt + WSZ;
        bf16_t* Qp  = WOt + WSZ;
        bf16_t* Kp  = Qp + SB;
        bf16_t* Vp  = Kp + SB;
        float*  Vm  = (float*)(Vp + SB);
        bf16_t* Cx  = Qp;
        bf16_t* VT  = Vb;

        wtrans<<<tg32, tb32, 0, stream>>>(WQ, WQt, 0.125f);
        wtrans<<<tg32, tb32, 0, stream>>>(WK, WKt, 1.0f);
        wtrans<<<tg32, tb32, 0, stream>>>(WV, WVt, 1.0f);
        wtrans<<<tg32, tb32, 0, stream>>>(WO, WOt, 1.0f);

        int cg = (int)(SB / (8 * 256));
        dim3 gg(2048 / 128, DM / 128);
        for (int b = 0; b < BATCH; ++b) {
            const size_t off = (size_t)b * SB;
            cvt_bf16<<<cg, 256, 0, stream>>>(Qe + off, Qb, (int)SB);
            cvt_bf16<<<cg, 256, 0, stream>>>(Ke + off, Kb, (int)SB);
            cvt_bf16<<<cg, 256, 0, stream>>>(Ve + off, Vb, (int)SB);
            gemm_nt_128<bf16_t><<<gg, 256, 0, stream>>>(Qb, WQt, Qp, 2048, DM, DM, 1.0f);
            gemm_nt_128<bf16_t><<<gg, 256, 0, stream>>>(Kb, WKt, Kp, 2048, DM, DM, 1.0f);
            gemm_nt_128<bf16_t><<<gg, 256, 0, stream>>>(Vb, WVt, Vp, 2048, DM, DM, 1.0f);
            btrans<<<dim3(DM / 32, 2048 / 32), tb32, 0, stream>>>(Vp, VT, 2048, DM);
            vmean_kernel<<<dim3(DM / 64, 1), 256, 0, stream>>>(Vp, Vm);
            attn_kernel<<<dim3(S_LEN / 64, NH, 1), 256, 0, stream>>>(
                Qp, Kp, VT, Kini + (size_t)b * S_LEN, Vm, Cx, 2048);
            gemm_nt_128<float><<<gg, 256, 0, stream>>>(Cx, WOt, out + off, 2048, DM, DM, 1.0f);
        }
    }
}

// Round 6
// 427.089 us; speedup vs baseline: 1.7913x; 1.7913x over previous
//
#include <hip/hip_runtime.h>

typedef __bf16 bf16_t;
typedef __bf16 bf16x8 __attribute__((ext_vector_type(8)));
typedef float  f32x4  __attribute__((ext_vector_type(4)));

#define S_LEN 2048
#define NH    16
#define DH    64
#define DM    1024
#define BATCH 4

static __device__ __forceinline__ f32x4 mfma16(bf16x8 a, bf16x8 b, f32x4 c) {
    return __builtin_amdgcn_mfma_f32_16x16x32_bf16(a, b, c, 0, 0, 0);
}

// async global->LDS, 16B per lane. lds base is wave-uniform; HW adds lane*16.
static __device__ __forceinline__ void gl_lds16(const bf16_t* g, bf16_t* l) {
    __builtin_amdgcn_global_load_lds(
        (const __attribute__((address_space(1))) unsigned int*)g,
        (__attribute__((address_space(3))) unsigned int*)l, 16, 0, 0);
}

// ---------------- fp32 -> bf16 elementwise convert (8 elems/thread) ----------
__global__ __launch_bounds__(256) void cvt_bf16(const float* __restrict__ s,
                                                bf16_t* __restrict__ d, int n) {
    int i = (blockIdx.x * 256 + threadIdx.x) * 8;
    if (i >= n) return;
    const float4* q = (const float4*)(s + i);
    float4 a = q[0], b = q[1];
    bf16x8 r;
    r[0] = (bf16_t)a.x; r[1] = (bf16_t)a.y; r[2] = (bf16_t)a.z; r[3] = (bf16_t)a.w;
    r[4] = (bf16_t)b.x; r[5] = (bf16_t)b.y; r[6] = (bf16_t)b.z; r[7] = (bf16_t)b.w;
    *(bf16x8*)(d + i) = r;
}

// ---------------- weight transpose+convert: Wt[n][k] = scale * W[k][n] -------
__global__ __launch_bounds__(256) void wtrans(const float* __restrict__ W,
                                              bf16_t* __restrict__ Wt, float scale) {
    __shared__ bf16_t tile[32][33];
    int x = threadIdx.x, ty = threadIdx.y;
    int bx = blockIdx.x * 32, by = blockIdx.y * 32;
#pragma unroll
    for (int i = 0; i < 4; ++i) {
        int y = ty * 4 + i;
        tile[y][x] = (bf16_t)(W[(by + y) * DM + bx + x] * scale);
    }
    __syncthreads();
#pragma unroll
    for (int i = 0; i < 4; ++i) {
        int y = ty * 4 + i;
        Wt[(bx + y) * DM + by + x] = tile[x][y];
    }
}

// ---------------- bf16 transpose: dst[C][R] = src[R][C] ----------------------
__global__ __launch_bounds__(256) void btrans(const bf16_t* __restrict__ src,
                                              bf16_t* __restrict__ dst,
                                              int R, int C) {
    __shared__ bf16_t tile[32][33];
    int x = threadIdx.x, ty = threadIdx.y;
    int bx = blockIdx.x * 32, by = blockIdx.y * 32;   // bx: col, by: row
#pragma unroll
    for (int i = 0; i < 4; ++i) {
        int y = ty * 4 + i;
        tile[y][x] = src[(size_t)(by + y) * C + bx + x];
    }
    __syncthreads();
#pragma unroll
    for (int i = 0; i < 4; ++i) {
        int y = ty * 4 + i;
        dst[(size_t)(bx + y) * R + by + x] = tile[x][y];
    }
}

// ---------------- NT GEMM (m97 structure): C = alpha * A[M][K] . Bt[N][K]^T --
// 128x128 tile, BK=32, global_load_lds width-16 staging, 4 waves, 4x4 frags.
template <typename CT>
__global__ __launch_bounds__(256) void gemm_nt_128(const bf16_t* __restrict__ A,
                                                   const bf16_t* __restrict__ Bt,
                                                   CT* __restrict__ C,
                                                   int M, int N, int K, float alpha) {
    __shared__ __align__(16) bf16_t As[128 * 32];  // unpadded: global_load_lds layout
    __shared__ __align__(16) bf16_t Bs[128 * 32];
    int tid = threadIdx.x, wave = tid >> 6, lane = tid & 63;
    int l15 = lane & 15, quad = lane >> 4;
    int wm = wave >> 1, wn = wave & 1;
    int bm = blockIdx.x * 128, bn = blockIdx.y * 128;
    int lrow = lane >> 2, lk = (lane & 3) << 3;

    f32x4 acc[4][4] = {};

    for (int k0 = 0; k0 < K; k0 += 32) {
#pragma unroll
        for (int c = 0; c < 2; ++c) {
            int r = wave * 32 + c * 16 + lrow;            // tile row this lane fetches
            gl_lds16(A  + (size_t)(bm + r) * K + k0 + lk, As + (wave * 2 + c) * 512);
            gl_lds16(Bt + (size_t)(bn + r) * K + k0 + lk, Bs + (wave * 2 + c) * 512);
        }
        __syncthreads();   // compiler drains vmcnt before s_barrier

        bf16x8 af[4], bfr[4];
#pragma unroll
        for (int i = 0; i < 4; ++i)
            af[i] = *(const bf16x8*)(As + (wm * 64 + i * 16 + l15) * 32 + quad * 8);
#pragma unroll
        for (int j = 0; j < 4; ++j)
            bfr[j] = *(const bf16x8*)(Bs + (wn * 64 + j * 16 + l15) * 32 + quad * 8);
#pragma unroll
        for (int i = 0; i < 4; ++i)
#pragma unroll
            for (int j = 0; j < 4; ++j)
                acc[i][j] = mfma16(af[i], bfr[j], acc[i][j]);
        __syncthreads();
    }

#pragma unroll
    for (int i = 0; i < 4; ++i)
#pragma unroll
        for (int r = 0; r < 4; ++r) {
            int row = bm + wm * 64 + i * 16 + quad * 4 + r;
#pragma unroll
            for (int j = 0; j < 4; ++j)
                C[(size_t)row * N + bn + wn * 64 + j * 16 + l15] =
                    (CT)(acc[i][j][r] * alpha);
        }
}

// ---------------- per-batch V column mean (for fully-masked-row fallback) ----
__global__ __launch_bounds__(256) void vmean_kernel(const bf16_t* __restrict__ Vp,
                                                    float* __restrict__ Vm) {
    __shared__ float red[4][64];
    int z = blockIdx.y;
    int c = blockIdx.x * 64 + (threadIdx.x & 63);
    int rg = threadIdx.x >> 6;
    const bf16_t* p = Vp + (size_t)z * S_LEN * DM + (size_t)rg * (S_LEN / 4) * DM + c;
    float s = 0.f;
    for (int r = 0; r < S_LEN / 4; ++r) s += (float)p[(size_t)r * DM];
    red[rg][threadIdx.x & 63] = s;
    __syncthreads();
    if (threadIdx.x < 64) {
        float t = red[0][threadIdx.x] + red[1][threadIdx.x] +
                  red[2][threadIdx.x] + red[3][threadIdx.x];
        Vm[z * DM + blockIdx.x * 64 + threadIdx.x] = t * (1.0f / S_LEN);
    }
}

// ---------------- fused attention: LDS-staged K/V, prefetch, heavy-first -----
// 1D grid of (S/64)*NH*nb blocks; qt decreasing with blockIdx so heavy (long)
// blocks launch first. K staged from Kp [s][h*64+dh]; V staged from VT
// [h*64+dh][ldv] (pre-transposed) -> both sides pure b128, no scatter.
// Register prefetch of tile k+1's global loads overlaps tile k's compute.
// Mask semantics exact as reference (score - 1e10, fp32 absorption); rows with
// no unmasked key fall back to Vmean (uniform softmax over all 2048 keys).
// ctx may alias Qp: block reads only its own (rows x head) slice at start and
// writes only that same slice at the end; slices are disjoint across blocks.
__global__ __launch_bounds__(256) void attn_kernel(const bf16_t* __restrict__ Qp,
                                                   const bf16_t* __restrict__ Kp,
                                                   const bf16_t* __restrict__ VT,
                                                   const int* __restrict__ Kini,
                                                   const float* __restrict__ Vmean,
                                                   bf16_t* __restrict__ ctx,
                                                   int ldv, int nqt) {
    __shared__ __align__(16) bf16_t Ks[64 * 72];     // [key][dh], stride 72
    __shared__ __align__(16) bf16_t VsT[64 * 72];    // [dh][key], stride 72
    __shared__ __align__(16) bf16_t Ps[4][16 * 72];  // per-wave P [qrow][key]

    int bid = blockIdx.x;
    int qt = nqt - 1 - (bid >> 6);                   // heavy tiles first
    int hz = bid & 63;
    int h = hz & 15, z = hz >> 4;
    int tid = threadIdx.x, wave = tid >> 6, lane = tid & 63;
    int l15 = lane & 15, quad = lane >> 4;
    int qbase = qt * 64 + wave * 16;
    size_t rowz = (size_t)z * S_LEN;

    const bf16_t* qptr = Qp + (rowz + qbase + l15) * DM + h * DH + quad * 8;
    bf16x8 qa0 = *(const bf16x8*)qptr;
    bf16x8 qa1 = *(const bf16x8*)(qptr + 32);

    f32x4 o[4] = {};
    float m_[4], l_[4];
#pragma unroll
    for (int r = 0; r < 4; ++r) { m_[r] = -3.0e38f; l_[r] = 0.0f; }

    // staging assignment: 256 threads cover 64 rows x 64 elems, 2 b128 each
    int srow = tid >> 2, sch = (tid & 3) << 4;       // row 0..63, chunk 0/16/32/48
    const bf16_t* kgb = Kp + (rowz + srow) * DM + h * DH + sch;      // + kb*DM
    const bf16_t* vgb = VT + (size_t)(h * DH + srow) * ldv + rowz + sch;  // + kb

    int ntiles = qt + 1;                             // causal: only kb <= q_max

    // prefetch tile 0
    bf16x8 kr0 = *(const bf16x8*)kgb,        kr1 = *(const bf16x8*)(kgb + 8);
    bf16x8 vr0 = *(const bf16x8*)vgb,        vr1 = *(const bf16x8*)(vgb + 8);

    for (int kt = 0; kt < ntiles; ++kt) {
        int kb = kt * 64;
        // stage prefetched tile into LDS (pure b128 both tensors)
        *(bf16x8*)(Ks  + srow * 72 + sch)     = kr0;
        *(bf16x8*)(Ks  + srow * 72 + sch + 8) = kr1;
        *(bf16x8*)(VsT + srow * 72 + sch)     = vr0;
        *(bf16x8*)(VsT + srow * 72 + sch + 8) = vr1;
        __syncthreads();

        // issue next tile's global loads (clamped at last iter; wave-uniform)
        int nkb = (kt + 1 < ntiles) ? kb + 64 : kb;
        const bf16_t* kg = kgb + (size_t)nkb * DM;
        const bf16_t* vg = vgb + nkb;
        kr0 = *(const bf16x8*)kg; kr1 = *(const bf16x8*)(kg + 8);
        vr0 = *(const bf16x8*)vg; vr1 = *(const bf16x8*)(vg + 8);

        // QK^T: 4 x 16-key subtiles, contraction over dh=64
        float sv[4][4];
#pragma unroll
        for (int ks = 0; ks < 4; ++ks) {
            bf16x8 kf0 = *(const bf16x8*)(Ks + (ks * 16 + l15) * 72 + quad * 8);
            bf16x8 kf1 = *(const bf16x8*)(Ks + (ks * 16 + l15) * 72 + 32 + quad * 8);
            f32x4 s = {0.f, 0.f, 0.f, 0.f};
            s = mfma16(qa0, kf0, s);
            s = mfma16(qa1, kf1, s);
            int key = kb + ks * 16 + l15;
            bool padz = (Kini[rowz + key] == 0);
#pragma unroll
            for (int r = 0; r < 4; ++r) {
                int q = qbase + quad * 4 + r;
                float val = s[r];
                if (padz || key > q) val -= 1e10f;   // additive mask, exact ref
                sv[ks][r] = val;
            }
        }

        // online softmax (stats reduced over the 16 lanes of each quad group)
#pragma unroll
        for (int r = 0; r < 4; ++r) {
            float mx = fmaxf(fmaxf(sv[0][r], sv[1][r]), fmaxf(sv[2][r], sv[3][r]));
#pragma unroll
            for (int d = 1; d < 16; d <<= 1) mx = fmaxf(mx, __shfl_xor(mx, d));
            float mn = fmaxf(m_[r], mx);
            float al = __expf(m_[r] - mn);
            float p0 = __expf(sv[0][r] - mn), p1 = __expf(sv[1][r] - mn);
            float p2 = __expf(sv[2][r] - mn), p3 = __expf(sv[3][r] - mn);
            float rs = (p0 + p1) + (p2 + p3);
#pragma unroll
            for (int d = 1; d < 16; d <<= 1) rs += __shfl_xor(rs, d);
            l_[r] = l_[r] * al + rs;
            m_[r] = mn;
#pragma unroll
            for (int j = 0; j < 4; ++j) o[j][r] *= al;
            int pr = (quad * 4 + r) * 72;
            Ps[wave][pr + l15]      = (bf16_t)p0;
            Ps[wave][pr + 16 + l15] = (bf16_t)p1;
            Ps[wave][pr + 32 + l15] = (bf16_t)p2;
            Ps[wave][pr + 48 + l15] = (bf16_t)p3;
        }

        // P (C-layout) -> A-layout via per-wave LDS round-trip (no barrier:
        // same-wave ds ordering, compiler inserts lgkmcnt)
        bf16x8 pa0 = *(const bf16x8*)(Ps[wave] + l15 * 72 + quad * 8);
        bf16x8 pa1 = *(const bf16x8*)(Ps[wave] + l15 * 72 + 32 + quad * 8);
#pragma unroll
        for (int j = 0; j < 4; ++j) {
            bf16x8 vb0 = *(const bf16x8*)(VsT + (j * 16 + l15) * 72 + quad * 8);
            bf16x8 vb1 = *(const bf16x8*)(VsT + (j * 16 + l15) * 72 + 32 + quad * 8);
            o[j] = mfma16(pa0, vb0, o[j]);
            o[j] = mfma16(pa1, vb1, o[j]);
        }
        __syncthreads();
    }

#pragma unroll
    for (int r = 0; r < 4; ++r) {
        int q = qbase + quad * 4 + r;
        float inv = 1.0f / l_[r];
        bf16_t* cp = ctx + (rowz + q) * DM + h * DH;
        if (m_[r] < -1e9f) {  // fully-masked row: ref softmax uniform over 2048
            const float* vm = Vmean + z * DM + h * DH;
#pragma unroll
            for (int j = 0; j < 4; ++j) cp[j * 16 + l15] = (bf16_t)vm[j * 16 + l15];
        } else {
#pragma unroll
            for (int j = 0; j < 4; ++j) cp[j * 16 + l15] = (bf16_t)(o[j][r] * inv);
        }
    }
}

extern "C" void kernel_launch(void* const* d_in, const int* in_sizes, int n_in,
                              void* d_out, int out_size, void* d_ws, size_t ws_size,
                              hipStream_t stream) {
    const float* Qe = (const float*)d_in[0];
    const float* Ke = (const float*)d_in[1];
    const float* Ve = (const float*)d_in[2];
    const int* Kini = (const int*)d_in[4];
    const float* WQ = (const float*)d_in[5];
    const float* WK = (const float*)d_in[6];
    const float* WV = (const float*)d_in[7];
    const float* WO = (const float*)d_in[8];
    float* out = (float*)d_out;

    const size_t EMB = (size_t)BATCH * S_LEN * DM;   // 8M elems
    const size_t SB  = (size_t)S_LEN * DM;           // 2M elems
    const size_t WSZ = (size_t)DM * DM;              // 1M elems
    const size_t need_full = (6 * EMB + 4 * WSZ) * sizeof(bf16_t)
                           + (size_t)BATCH * DM * sizeof(float);

    dim3 tb32(32, 8), tg32(32, 32);

    if (ws_size >= need_full) {
        // ---- full-batch path (M = 8192) ----
        bf16_t* Qb  = (bf16_t*)d_ws;
        bf16_t* Kb  = Qb + EMB;
        bf16_t* Vb  = Kb + EMB;                 // becomes VT after V-GEMM
        bf16_t* WQt = Vb + EMB;
        bf16_t* WKt = WQt + WSZ;
        bf16_t* WVt = WKt + WSZ;
        bf16_t* WOt = WVt + WSZ;
        bf16_t* Qp  = WOt + WSZ;
        bf16_t* Kp  = Qp + EMB;
        bf16_t* Vp  = Kp + EMB;
        float*  Vm  = (float*)(Vp + EMB);
        bf16_t* Cx  = Qp;   // alias, block-disjoint (see attn_kernel)
        bf16_t* VT  = Vb;   // reuse spent Vb buffer

        int cg = (int)(EMB / (8 * 256));
        cvt_bf16<<<cg, 256, 0, stream>>>(Qe, Qb, (int)EMB);
        cvt_bf16<<<cg, 256, 0, stream>>>(Ke, Kb, (int)EMB);
        cvt_bf16<<<cg, 256, 0, stream>>>(Ve, Vb, (int)EMB);
        wtrans<<<tg32, tb32, 0, stream>>>(WQ, WQt, 0.125f);  // fold 1/sqrt(dh)
        wtrans<<<tg32, tb32, 0, stream>>>(WK, WKt, 1.0f);
        wtrans<<<tg32, tb32, 0, stream>>>(WV, WVt, 1.0f);
        wtrans<<<tg32, tb32, 0, stream>>>(WO, WOt, 1.0f);

        dim3 gg(8192 / 128, DM / 128);
        gemm_nt_128<bf16_t><<<gg, 256, 0, stream>>>(Qb, WQt, Qp, 8192, DM, DM, 1.0f);
        gemm_nt_128<bf16_t><<<gg, 256, 0, stream>>>(Kb, WKt, Kp, 8192, DM, DM, 1.0f);
        gemm_nt_128<bf16_t><<<gg, 256, 0, stream>>>(Vb, WVt, Vp, 8192, DM, DM, 1.0f);

        btrans<<<dim3(DM / 32, 8192 / 32), tb32, 0, stream>>>(Vp, VT, 8192, DM);
        vmean_kernel<<<dim3(DM / 64, BATCH), 256, 0, stream>>>(Vp, Vm);
        attn_kernel<<<dim3((S_LEN / 64) * NH * BATCH), 256, 0, stream>>>(
            Qp, Kp, VT, Kini, Vm, Cx, 8192, S_LEN / 64);

        gemm_nt_128<float><<<gg, 256, 0, stream>>>(Cx, WOt, out, 8192, DM, DM, 1.0f);
    } else {
        // ---- per-batch fallback (M = 2048, ~34 MB workspace) ----
        bf16_t* Qb  = (bf16_t*)d_ws;
        bf16_t* Kb  = Qb + SB;
        bf16_t* Vb  = Kb + SB;
        bf16_t* WQt = Vb + SB;
        bf16_t* WKt = WQt + WSZ;
        bf16_t* WVt = WKt + WSZ;
        bf16_t* WOt = WVt + WSZ;
        bf16_t* Qp  = WOt + WSZ;
        bf16_t* Kp  = Qp + SB;
        bf16_t* Vp  = Kp + SB;
        float*  Vm  = (float*)(Vp + SB);
        bf16_t* Cx  = Qp;
        bf16_t* VT  = Vb;

        wtrans<<<tg32, tb32, 0, stream>>>(WQ, WQt, 0.125f);
        wtrans<<<tg32, tb32, 0, stream>>>(WK, WKt, 1.0f);
        wtrans<<<tg32, tb32, 0, stream>>>(WV, WVt, 1.0f);
        wtrans<<<tg32, tb32, 0, stream>>>(WO, WOt, 1.0f);

        int cg = (int)(SB / (8 * 256));
        dim3 gg(2048 / 128, DM / 128);
        for (int b = 0; b < BATCH; ++b) {
            const size_t off = (size_t)b * SB;
            cvt_bf16<<<cg, 256, 0, stream>>>(Qe + off, Qb, (int)SB);
            cvt_bf16<<<cg, 256, 0, stream>>>(Ke + off, Kb, (int)SB);
            cvt_bf16<<<cg, 256, 0, stream>>>(Ve + off, Vb, (int)SB);
            gemm_nt_128<bf16_t><<<gg, 256, 0, stream>>>(Qb, WQt, Qp, 2048, DM, DM, 1.0f);
            gemm_nt_128<bf16_t><<<gg, 256, 0, stream>>>(Kb, WKt, Kp, 2048, DM, DM, 1.0f);
            gemm_nt_128<bf16_t><<<gg, 256, 0, stream>>>(Vb, WVt, Vp, 2048, DM, DM, 1.0f);
            btrans<<<dim3(DM / 32, 2048 / 32), tb32, 0, stream>>>(Vp, VT, 2048, DM);
            vmean_kernel<<<dim3(DM / 64, 1), 256, 0, stream>>>(Vp, Vm);
            attn_kernel<<<dim3((S_LEN / 64) * NH), 256, 0, stream>>>(
                Qp, Kp, VT, Kini + (size_t)b * S_LEN, Vm, Cx, 2048, S_LEN / 64);
            gemm_nt_128<float><<<gg, 256, 0, stream>>>(Cx, WOt, out + off, 2048, DM, DM, 1.0f);
        }
    }
}